// Round 1
// baseline (1346.569 us; speedup 1.0000x reference)
//
#include <hip/hip_runtime.h>
#include <math.h>

#define B 16
#define N 4096
#define KNN 2          // k = min(5, x.shape[1]-1) with x.shape[1]==3  -> 2
#define C 21
#define CO 3           // only output channels 0..2 matter ([:, :3])
#define EPSF 1e-6f
#define BN_EPSD 1e-5

__device__ __forceinline__ float waveReduceSum(float v) {
#pragma unroll
    for (int m = 32; m > 0; m >>= 1) v += __shfl_xor(v, m, 64);
    return v;
}

// ---------------- K1: kNN (top-2 by pd = -||xi-xj||^2, f64 for ref-matching) --------
#define TB_KNN 128
__global__ __launch_bounds__(TB_KNN) void k_knn(const float* __restrict__ pc,
                                                int* __restrict__ nbr) {
    __shared__ float sx[N], sy[N], sz[N];
    const int bpb = N / TB_KNN;
    const int b = blockIdx.x / bpb;
    const int n = (blockIdx.x % bpb) * TB_KNN + threadIdx.x;
    const float* base = pc + (size_t)b * (N * 3);
    for (int j = threadIdx.x; j < N; j += TB_KNN) {
        sx[j] = base[3 * j + 0];
        sy[j] = base[3 * j + 1];
        sz[j] = base[3 * j + 2];
    }
    __syncthreads();
    const double qx = sx[n], qy = sy[n], qz = sz[n];
    double v0 = -1e300, v1 = -1e300;
    int i0 = 0, i1 = 0;
    for (int j = 0; j < N; ++j) {
        double dx = qx - (double)sx[j];
        double dy = qy - (double)sy[j];
        double dz = qz - (double)sz[j];
        double pd = -(dx * dx + dy * dy + dz * dz);
        if (pd > v1) {
            bool g0 = pd > v0;
            v1 = g0 ? v0 : pd;  i1 = g0 ? i0 : j;
            v0 = g0 ? pd : v0;  i0 = g0 ? j  : i0;
        }
    }
    int* o = nbr + ((size_t)b * N + n) * KNN;
    o[0] = i0;
    o[1] = i1;
}

// ---------------- K2: layer0 BN stats (norm of p over (B,N,k) per channel) ----------
__global__ __launch_bounds__(256) void k_l0_stats(const float* __restrict__ pc,
                                                  const int* __restrict__ nbr,
                                                  const float* __restrict__ Wf0,
                                                  double* __restrict__ stats0) {
    __shared__ float wf[C * 3];
    if (threadIdx.x < C * 3) wf[threadIdx.x] = Wf0[threadIdx.x];
    __syncthreads();
    const int t = blockIdx.x * 256 + threadIdx.x;
    const int b = t / N, n = t % N;
    const float* base = pc + (size_t)b * (N * 3);
    const float cx = base[3 * n], cy = base[3 * n + 1], cz = base[3 * n + 2];
    float s1[C], s2[C];
#pragma unroll
    for (int o = 0; o < C; ++o) { s1[o] = 0.f; s2[o] = 0.f; }
    const int* my = nbr + (size_t)t * KNN;
#pragma unroll
    for (int k = 0; k < KNN; ++k) {
        int j = my[k];
        float nx = base[3 * j], ny = base[3 * j + 1], nz = base[3 * j + 2];
        float e0x = nx - cx, e0y = ny - cy, e0z = nz - cz;
        float e2x = ny * cz - nz * cy;
        float e2y = nz * cx - nx * cz;
        float e2z = nx * cy - ny * cx;
#pragma unroll
        for (int o = 0; o < C; ++o) {
            float w0 = wf[3 * o], w1 = wf[3 * o + 1], w2 = wf[3 * o + 2];
            float px = w0 * e0x + w1 * cx + w2 * e2x;
            float py = w0 * e0y + w1 * cy + w2 * e2y;
            float pz = w0 * e0z + w1 * cz + w2 * e2z;
            float norm = sqrtf(px * px + py * py + pz * pz) + EPSF;
            s1[o] += norm;
            s2[o] += norm * norm;
        }
    }
    const int lane = threadIdx.x & 63;
#pragma unroll
    for (int o = 0; o < C; ++o) {
        float r1 = waveReduceSum(s1[o]);
        float r2 = waveReduceSum(s2[o]);
        if (lane == 0) {
            atomicAdd(&stats0[2 * o], (double)r1);
            atomicAdd(&stats0[2 * o + 1], (double)r2);
        }
    }
}

// ---------------- K3: layer0 apply (BN + leaky + mean over k) -> out0 (B,C,3,N) -----
__global__ __launch_bounds__(256) void k_l0_apply(const float* __restrict__ pc,
                                                  const int* __restrict__ nbr,
                                                  const float* __restrict__ Wf0,
                                                  const float* __restrict__ Wd0,
                                                  const float* __restrict__ g0,
                                                  const float* __restrict__ bt0,
                                                  const double* __restrict__ stats0,
                                                  float* __restrict__ out0) {
    __shared__ float wf[C * 3], wd[C * 3], mu[C], isd[C], gg[C], bb[C];
    if (threadIdx.x < C * 3) {
        wf[threadIdx.x] = Wf0[threadIdx.x];
        wd[threadIdx.x] = Wd0[threadIdx.x];
    }
    if (threadIdx.x < C) {
        const double M = (double)B * N * KNN;
        double m = stats0[2 * threadIdx.x] / M;
        double v = stats0[2 * threadIdx.x + 1] / M - m * m;
        mu[threadIdx.x] = (float)m;
        isd[threadIdx.x] = (float)(1.0 / sqrt(v + BN_EPSD));
        gg[threadIdx.x] = g0[threadIdx.x];
        bb[threadIdx.x] = bt0[threadIdx.x];
    }
    __syncthreads();
    const int t = blockIdx.x * 256 + threadIdx.x;
    const int b = t / N, n = t % N;
    const float* base = pc + (size_t)b * (N * 3);
    const float cx = base[3 * n], cy = base[3 * n + 1], cz = base[3 * n + 2];
    float ax[C], ay[C], az[C];
#pragma unroll
    for (int o = 0; o < C; ++o) { ax[o] = 0.f; ay[o] = 0.f; az[o] = 0.f; }
    const int* my = nbr + (size_t)t * KNN;
#pragma unroll
    for (int k = 0; k < KNN; ++k) {
        int j = my[k];
        float nx = base[3 * j], ny = base[3 * j + 1], nz = base[3 * j + 2];
        float e0x = nx - cx, e0y = ny - cy, e0z = nz - cz;
        float e2x = ny * cz - nz * cy;
        float e2y = nz * cx - nx * cz;
        float e2z = nx * cy - ny * cx;
#pragma unroll
        for (int o = 0; o < C; ++o) {
            float w0 = wf[3 * o], w1 = wf[3 * o + 1], w2 = wf[3 * o + 2];
            float px = w0 * e0x + w1 * cx + w2 * e2x;
            float py = w0 * e0y + w1 * cy + w2 * e2y;
            float pz = w0 * e0z + w1 * cz + w2 * e2z;
            float u0 = wd[3 * o], u1 = wd[3 * o + 1], u2 = wd[3 * o + 2];
            float dx = u0 * e0x + u1 * cx + u2 * e2x;
            float dy = u0 * e0y + u1 * cy + u2 * e2y;
            float dz = u0 * e0z + u1 * cz + u2 * e2z;
            float norm = sqrtf(px * px + py * py + pz * pz) + EPSF;
            float nbn = (norm - mu[o]) * isd[o] * gg[o] + bb[o];
            float s = nbn / norm;
            float dotr = px * dx + py * dy + pz * dz;
            float dsq = dx * dx + dy * dy + dz * dz;
            float dot = s * dotr;
            float coef = (dot >= 0.f) ? 0.f : (dot / (dsq + EPSF));
            ax[o] += s * px - coef * dx;
            ay[o] += s * py - coef * dy;
            az[o] += s * pz - coef * dz;
        }
    }
    const float inv = 1.f / (float)KNN;
#pragma unroll
    for (int o = 0; o < C; ++o) {
        size_t ib = (((size_t)b * C + o) * 3) * N + n;
        out0[ib] = ax[o] * inv;
        out0[ib + N] = ay[o] * inv;
        out0[ib + 2 * N] = az[o] * inv;
    }
}

// ---------------- K4: layer1 BN stats ------------------------------------------------
__global__ __launch_bounds__(256) void k_l1_stats(const float* __restrict__ data,
                                                  const float* __restrict__ Wf1,
                                                  double* __restrict__ stats1) {
    __shared__ float wf[C * C];
    for (int i = threadIdx.x; i < C * C; i += 256) wf[i] = Wf1[i];
    __syncthreads();
    const int t = blockIdx.x * 256 + threadIdx.x;
    const int b = t / N, n = t % N;
    float x[C][3];
#pragma unroll
    for (int c = 0; c < C; ++c) {
        size_t ib = (((size_t)b * C + c) * 3) * N + n;
        x[c][0] = data[ib];
        x[c][1] = data[ib + N];
        x[c][2] = data[ib + 2 * N];
    }
    const int lane = threadIdx.x & 63;
#pragma unroll
    for (int o = 0; o < C; ++o) {
        float px = 0.f, py = 0.f, pz = 0.f;
#pragma unroll
        for (int c = 0; c < C; ++c) {
            float w = wf[o * C + c];
            px += w * x[c][0];
            py += w * x[c][1];
            pz += w * x[c][2];
        }
        float norm = sqrtf(px * px + py * py + pz * pz) + EPSF;
        float r1 = waveReduceSum(norm);
        float r2 = waveReduceSum(norm * norm);
        if (lane == 0) {
            atomicAdd(&stats1[2 * o], (double)r1);
            atomicAdd(&stats1[2 * o + 1], (double)r2);
        }
    }
}

// ---------------- K5: layer1 apply (in-place) + bn1 stats ---------------------------
__global__ __launch_bounds__(256) void k_l1_apply(float* __restrict__ data,
                                                  const float* __restrict__ Wf1,
                                                  const float* __restrict__ Wd1,
                                                  const float* __restrict__ g1,
                                                  const float* __restrict__ bt1,
                                                  const double* __restrict__ stats1,
                                                  double* __restrict__ statsB) {
    __shared__ float wf[C * C], wd[C * C], mu[C], isd[C], gg[C], bb[C];
    for (int i = threadIdx.x; i < C * C; i += 256) {
        wf[i] = Wf1[i];
        wd[i] = Wd1[i];
    }
    if (threadIdx.x < C) {
        const double M = (double)B * N;
        double m = stats1[2 * threadIdx.x] / M;
        double v = stats1[2 * threadIdx.x + 1] / M - m * m;
        mu[threadIdx.x] = (float)m;
        isd[threadIdx.x] = (float)(1.0 / sqrt(v + BN_EPSD));
        gg[threadIdx.x] = g1[threadIdx.x];
        bb[threadIdx.x] = bt1[threadIdx.x];
    }
    __syncthreads();
    const int t = blockIdx.x * 256 + threadIdx.x;
    const int b = t / N, n = t % N;
    float x[C][3];
#pragma unroll
    for (int c = 0; c < C; ++c) {
        size_t ib = (((size_t)b * C + c) * 3) * N + n;
        x[c][0] = data[ib];
        x[c][1] = data[ib + N];
        x[c][2] = data[ib + 2 * N];
    }
    const int lane = threadIdx.x & 63;
#pragma unroll
    for (int o = 0; o < C; ++o) {
        float px = 0.f, py = 0.f, pz = 0.f, dx = 0.f, dy = 0.f, dz = 0.f;
#pragma unroll
        for (int c = 0; c < C; ++c) {
            float w = wf[o * C + c], u = wd[o * C + c];
            px += w * x[c][0]; py += w * x[c][1]; pz += w * x[c][2];
            dx += u * x[c][0]; dy += u * x[c][1]; dz += u * x[c][2];
        }
        float norm = sqrtf(px * px + py * py + pz * pz) + EPSF;
        float nbn = (norm - mu[o]) * isd[o] * gg[o] + bb[o];
        float s = nbn / norm;
        float dotr = px * dx + py * dy + pz * dz;
        float dsq = dx * dx + dy * dy + dz * dz;
        float dot = s * dotr;
        float coef = (dot >= 0.f) ? 0.f : (dot / (dsq + EPSF));
        float ox = s * px - coef * dx;
        float oy = s * py - coef * dy;
        float oz = s * pz - coef * dz;
        size_t ib = (((size_t)b * C + o) * 3) * N + n;
        data[ib] = ox;
        data[ib + N] = oy;
        data[ib + 2 * N] = oz;
        float onorm = sqrtf(ox * ox + oy * oy + oz * oz) + EPSF;
        float r1 = waveReduceSum(onorm);
        float r2 = waveReduceSum(onorm * onorm);
        if (lane == 0) {
            atomicAdd(&statsB[2 * o], (double)r1);
            atomicAdd(&statsB[2 * o + 1], (double)r2);
        }
    }
}

// ---------------- K6: bn1-normalize + layer2 BN stats (channels 0..2) ---------------
__global__ __launch_bounds__(256) void k_l2_stats(const float* __restrict__ data,
                                                  const float* __restrict__ Wf2,
                                                  const float* __restrict__ gbn,
                                                  const float* __restrict__ bbn,
                                                  const double* __restrict__ statsB,
                                                  double* __restrict__ stats2) {
    __shared__ float wf[CO * C], muB[C], isdB[C], gB[C], bB[C];
    if (threadIdx.x < CO * C) wf[threadIdx.x] = Wf2[threadIdx.x];
    if (threadIdx.x < C) {
        const double M = (double)B * N;
        double m = statsB[2 * threadIdx.x] / M;
        double v = statsB[2 * threadIdx.x + 1] / M - m * m;
        muB[threadIdx.x] = (float)m;
        isdB[threadIdx.x] = (float)(1.0 / sqrt(v + BN_EPSD));
        gB[threadIdx.x] = gbn[threadIdx.x];
        bB[threadIdx.x] = bbn[threadIdx.x];
    }
    __syncthreads();
    const int t = blockIdx.x * 256 + threadIdx.x;
    const int b = t / N, n = t % N;
    float y[C][3];
#pragma unroll
    for (int c = 0; c < C; ++c) {
        size_t ib = (((size_t)b * C + c) * 3) * N + n;
        float x0 = data[ib], x1 = data[ib + N], x2 = data[ib + 2 * N];
        float norm = sqrtf(x0 * x0 + x1 * x1 + x2 * x2) + EPSF;
        float nbn = (norm - muB[c]) * isdB[c] * gB[c] + bB[c];
        float sc = nbn / norm;
        y[c][0] = sc * x0; y[c][1] = sc * x1; y[c][2] = sc * x2;
    }
    const int lane = threadIdx.x & 63;
#pragma unroll
    for (int o = 0; o < CO; ++o) {
        float px = 0.f, py = 0.f, pz = 0.f;
#pragma unroll
        for (int c = 0; c < C; ++c) {
            float w = wf[o * C + c];
            px += w * y[c][0]; py += w * y[c][1]; pz += w * y[c][2];
        }
        float norm = sqrtf(px * px + py * py + pz * pz) + EPSF;
        float r1 = waveReduceSum(norm);
        float r2 = waveReduceSum(norm * norm);
        if (lane == 0) {
            atomicAdd(&stats2[2 * o], (double)r1);
            atomicAdd(&stats2[2 * o + 1], (double)r2);
        }
    }
}

// ---------------- K7: layer2 apply + mean over N (block partials -> double atomics) --
__global__ __launch_bounds__(256) void k_l2_apply(const float* __restrict__ data,
                                                  const float* __restrict__ Wf2,
                                                  const float* __restrict__ Wd2,
                                                  const float* __restrict__ g2,
                                                  const float* __restrict__ bt2,
                                                  const float* __restrict__ gbn,
                                                  const float* __restrict__ bbn,
                                                  const double* __restrict__ statsB,
                                                  const double* __restrict__ stats2,
                                                  double* __restrict__ accum) {
    __shared__ float wf[CO * C], wd[CO * C], muB[C], isdB[C], gB[C], bB[C];
    __shared__ float mu2[CO], isd2[CO], g2s[CO], b2s[CO];
    if (threadIdx.x < CO * C) {
        wf[threadIdx.x] = Wf2[threadIdx.x];
        wd[threadIdx.x] = Wd2[threadIdx.x];
    }
    if (threadIdx.x < C) {
        const double M = (double)B * N;
        double m = statsB[2 * threadIdx.x] / M;
        double v = statsB[2 * threadIdx.x + 1] / M - m * m;
        muB[threadIdx.x] = (float)m;
        isdB[threadIdx.x] = (float)(1.0 / sqrt(v + BN_EPSD));
        gB[threadIdx.x] = gbn[threadIdx.x];
        bB[threadIdx.x] = bbn[threadIdx.x];
    }
    if (threadIdx.x < CO) {
        const double M = (double)B * N;
        double m = stats2[2 * threadIdx.x] / M;
        double v = stats2[2 * threadIdx.x + 1] / M - m * m;
        mu2[threadIdx.x] = (float)m;
        isd2[threadIdx.x] = (float)(1.0 / sqrt(v + BN_EPSD));
        g2s[threadIdx.x] = g2[threadIdx.x];
        b2s[threadIdx.x] = bt2[threadIdx.x];
    }
    __syncthreads();
    const int t = blockIdx.x * 256 + threadIdx.x;
    const int b = t / N, n = t % N;
    float y[C][3];
#pragma unroll
    for (int c = 0; c < C; ++c) {
        size_t ib = (((size_t)b * C + c) * 3) * N + n;
        float x0 = data[ib], x1 = data[ib + N], x2 = data[ib + 2 * N];
        float norm = sqrtf(x0 * x0 + x1 * x1 + x2 * x2) + EPSF;
        float nbn = (norm - muB[c]) * isdB[c] * gB[c] + bB[c];
        float sc = nbn / norm;
        y[c][0] = sc * x0; y[c][1] = sc * x1; y[c][2] = sc * x2;
    }
    const int lane = threadIdx.x & 63;
#pragma unroll
    for (int o = 0; o < CO; ++o) {
        float px = 0.f, py = 0.f, pz = 0.f, dx = 0.f, dy = 0.f, dz = 0.f;
#pragma unroll
        for (int c = 0; c < C; ++c) {
            float w = wf[o * C + c], u = wd[o * C + c];
            px += w * y[c][0]; py += w * y[c][1]; pz += w * y[c][2];
            dx += u * y[c][0]; dy += u * y[c][1]; dz += u * y[c][2];
        }
        float norm = sqrtf(px * px + py * py + pz * pz) + EPSF;
        float nbn = (norm - mu2[o]) * isd2[o] * g2s[o] + b2s[o];
        float s = nbn / norm;
        float dotr = px * dx + py * dy + pz * dz;
        float dsq = dx * dx + dy * dy + dz * dz;
        float dot = s * dotr;
        float coef = (dot >= 0.f) ? 0.f : (dot / (dsq + EPSF));
        float ox = s * px - coef * dx;
        float oy = s * py - coef * dy;
        float oz = s * pz - coef * dz;
        float rx = waveReduceSum(ox);
        float ry = waveReduceSum(oy);
        float rz = waveReduceSum(oz);
        if (lane == 0) {
            atomicAdd(&accum[(size_t)b * 9 + o * 3 + 0], (double)rx);
            atomicAdd(&accum[(size_t)b * 9 + o * 3 + 1], (double)ry);
            atomicAdd(&accum[(size_t)b * 9 + o * 3 + 2], (double)rz);
        }
    }
}

// ---------------- K8: finalize -------------------------------------------------------
__global__ void k_final(const double* __restrict__ accum, float* __restrict__ out) {
    int i = threadIdx.x;
    if (i < B * 9) out[i] = (float)(accum[i] / (double)N);
}

extern "C" void kernel_launch(void* const* d_in, const int* in_sizes, int n_in,
                              void* d_out, int out_size, void* d_ws, size_t ws_size,
                              hipStream_t stream) {
    const float* pc  = (const float*)d_in[0];
    const float* Wf0 = (const float*)d_in[1];
    const float* Wd0 = (const float*)d_in[2];
    const float* g0  = (const float*)d_in[3];
    const float* b0  = (const float*)d_in[4];
    const float* Wf1 = (const float*)d_in[5];
    const float* Wd1 = (const float*)d_in[6];
    const float* g1  = (const float*)d_in[7];
    const float* b1  = (const float*)d_in[8];
    const float* gbn1 = (const float*)d_in[9];
    const float* bbn1 = (const float*)d_in[10];
    const float* Wf2 = (const float*)d_in[11];
    const float* Wd2 = (const float*)d_in[12];
    const float* g2  = (const float*)d_in[13];
    const float* b2  = (const float*)d_in[14];
    float* out = (float*)d_out;

    char* ws = (char*)d_ws;
    double* stats0 = (double*)ws;        // 42 doubles
    double* stats1 = stats0 + 42;        // 42
    double* statsB = stats1 + 42;        // 42
    double* stats2 = statsB + 42;        // 8
    double* accum  = stats2 + 8;         // 144
    int* nbr = (int*)(ws + 4096);                                   // B*N*KNN ints
    float* buf = (float*)(ws + 4096 + (size_t)B * N * KNN * sizeof(int)); // B*C*3*N floats (reused in-place)

    hipMemsetAsync(d_ws, 0, 4096, stream);  // zero all accumulators

    k_knn<<<B * (N / TB_KNN), TB_KNN, 0, stream>>>(pc, nbr);
    k_l0_stats<<<B * N / 256, 256, 0, stream>>>(pc, nbr, Wf0, stats0);
    k_l0_apply<<<B * N / 256, 256, 0, stream>>>(pc, nbr, Wf0, Wd0, g0, b0, stats0, buf);
    k_l1_stats<<<B * N / 256, 256, 0, stream>>>(buf, Wf1, stats1);
    k_l1_apply<<<B * N / 256, 256, 0, stream>>>(buf, Wf1, Wd1, g1, b1, stats1, statsB);
    k_l2_stats<<<B * N / 256, 256, 0, stream>>>(buf, Wf2, gbn1, bbn1, statsB, stats2);
    k_l2_apply<<<B * N / 256, 256, 0, stream>>>(buf, Wf2, Wd2, g2, b2, gbn1, bbn1, statsB, stats2, accum);
    k_final<<<1, 256, 0, stream>>>(accum, out);
}

// Round 3
// 334.055 us; speedup vs baseline: 4.0310x; 4.0310x over previous
//
#include <hip/hip_runtime.h>
#include <math.h>

#define B 16
#define N 4096
#define EPSF 1e-6f

__device__ __forceinline__ float waveReduceSum(float v) {
#pragma unroll
    for (int m = 32; m > 0; m >>= 1) v += __shfl_xor(v, m, 64);
    return v;
}

__device__ __forceinline__ void leaky3(float px, float py, float pz,
                                       float dx, float dy, float dz, float s,
                                       float& ox, float& oy, float& oz) {
    float dotr = px * dx + py * dy + pz * dz;
    float dsq = dx * dx + dy * dy + dz * dz;
    float dot = s * dotr;
    float coef = (dot >= 0.f) ? 0.f : (dot / (dsq + EPSF));
    ox = s * px - coef * dx;
    oy = s * py - coef * dy;
    oz = s * pz - coef * dz;
}

// Block-reduce NV per-thread f32 values -> one f64 atomicAdd per value per block.
template <int NV>
__device__ __forceinline__ void block_stats(float (&sv)[NV], float* red,
                                            double* gstats) {
    const int wid = threadIdx.x >> 6, lane = threadIdx.x & 63;
#pragma unroll
    for (int v = 0; v < NV; ++v) {
        float r = waveReduceSum(sv[v]);
        if (lane == 0) red[wid * NV + v] = r;
    }
    __syncthreads();
    if (threadIdx.x < NV) {
        float s = red[threadIdx.x] + red[NV + threadIdx.x] +
                  red[2 * NV + threadIdx.x] + red[3 * NV + threadIdx.x];
        atomicAdd(&gstats[threadIdx.x], (double)s);
    }
}

__device__ __forceinline__ void mk_muisd(const double* st, int cnt, double M,
                                         float* smu, float* sisd) {
    const int i = threadIdx.x;
    if (i < cnt) {
        double m = st[i] / M;
        double v = st[cnt + i] / M - m * m;
        smu[i] = (float)m;
        sisd[i] = (float)(1.0 / sqrt(v + 1e-5));
    }
}

struct Feat {
    float cx, cy, cz, e0x, e0y, e0z, e2x, e2y, e2z;
};

__device__ __forceinline__ Feat make_feat(const float* __restrict__ pc,
                                          const int* __restrict__ nbr, int tid) {
    const int b = tid >> 12, n = tid & (N - 1);
    const float* base = pc + (size_t)b * (3 * N);
    Feat f;
    f.cx = base[3 * n];
    f.cy = base[3 * n + 1];
    f.cz = base[3 * n + 2];
    const int jn = nbr[tid];
    float nx = base[3 * jn], ny = base[3 * jn + 1], nz = base[3 * jn + 2];
    f.e0x = nx - f.cx;
    f.e0y = ny - f.cy;
    f.e0z = nz - f.cz;
    f.e2x = ny * f.cz - nz * f.cy;
    f.e2y = nz * f.cx - nx * f.cz;
    f.e2z = nx * f.cy - ny * f.cx;
    return f;
}

__device__ __forceinline__ void l0_apply(const Feat& f, const float* wf0,
                                         const float* wd0, const float* g,
                                         const float* bb, const float* mu,
                                         const float* isd, float x[21][3]) {
#pragma unroll
    for (int o = 0; o < 21; ++o) {
        float w0 = wf0[3 * o], w1 = wf0[3 * o + 1], w2 = wf0[3 * o + 2];
        float u0 = wd0[3 * o], u1 = wd0[3 * o + 1], u2 = wd0[3 * o + 2];
        // self neighbor: e0 = 0, cross = 0 exactly -> p = w1*c, d = u1*c
        float pSx = w1 * f.cx, pSy = w1 * f.cy, pSz = w1 * f.cz;
        float nS = sqrtf(pSx * pSx + pSy * pSy + pSz * pSz) + EPSF;
        float sS = ((nS - mu[o]) * isd[o] * g[o] + bb[o]) / nS;
        float oSx, oSy, oSz;
        leaky3(pSx, pSy, pSz, u1 * f.cx, u1 * f.cy, u1 * f.cz, sS, oSx, oSy, oSz);
        // nearest neighbor
        float px = w0 * f.e0x + w1 * f.cx + w2 * f.e2x;
        float py = w0 * f.e0y + w1 * f.cy + w2 * f.e2y;
        float pz = w0 * f.e0z + w1 * f.cz + w2 * f.e2z;
        float dx = u0 * f.e0x + u1 * f.cx + u2 * f.e2x;
        float dy = u0 * f.e0y + u1 * f.cy + u2 * f.e2y;
        float dz = u0 * f.e0z + u1 * f.cz + u2 * f.e2z;
        float nN = sqrtf(px * px + py * py + pz * pz) + EPSF;
        float sN = ((nN - mu[o]) * isd[o] * g[o] + bb[o]) / nN;
        float oNx, oNy, oNz;
        leaky3(px, py, pz, dx, dy, dz, sN, oNx, oNy, oNz);
        x[o][0] = 0.5f * (oSx + oNx);
        x[o][1] = 0.5f * (oSy + oNy);
        x[o][2] = 0.5f * (oSz + oNz);
    }
}

__device__ __forceinline__ void l1_apply(float x[21][3], const float* wf1,
                                         const float* wd1, const float* g,
                                         const float* bb, const float* mu,
                                         const float* isd) {
    float nx[21][3];
#pragma unroll
    for (int o = 0; o < 21; ++o) {
        float px = 0.f, py = 0.f, pz = 0.f, dx = 0.f, dy = 0.f, dz = 0.f;
#pragma unroll
        for (int c = 0; c < 21; ++c) {
            float w = wf1[o * 21 + c], u = wd1[o * 21 + c];
            px += w * x[c][0]; py += w * x[c][1]; pz += w * x[c][2];
            dx += u * x[c][0]; dy += u * x[c][1]; dz += u * x[c][2];
        }
        float nn = sqrtf(px * px + py * py + pz * pz) + EPSF;
        float s = ((nn - mu[o]) * isd[o] * g[o] + bb[o]) / nn;
        leaky3(px, py, pz, dx, dy, dz, s, nx[o][0], nx[o][1], nx[o][2]);
    }
#pragma unroll
    for (int o = 0; o < 21; ++o) {
        x[o][0] = nx[o][0]; x[o][1] = nx[o][1]; x[o][2] = nx[o][2];
    }
}

__device__ __forceinline__ void bn1_apply(float x[21][3], const float* g,
                                          const float* bb, const float* mu,
                                          const float* isd) {
#pragma unroll
    for (int c = 0; c < 21; ++c) {
        float nn = sqrtf(x[c][0] * x[c][0] + x[c][1] * x[c][1] +
                         x[c][2] * x[c][2]) + EPSF;
        float sc = ((nn - mu[c]) * isd[c] * g[c] + bb[c]) / nn;
        x[c][0] *= sc; x[c][1] *= sc; x[c][2] *= sc;
    }
}

// ---------------- K1: nearest other point (argmax of pd over j!=i, f64) ------------
#define QW 4
__global__ __launch_bounds__(256) void k_knn(const float* __restrict__ pc,
                                             int* __restrict__ nbrbest) {
    __shared__ float sx[N], sy[N], sz[N];
    const int b = blockIdx.x >> 8;
    const int qblk = (blockIdx.x & 255) * 16;
    const float* base = pc + (size_t)b * (N * 3);
    for (int j = threadIdx.x; j < N; j += 256) {
        sx[j] = base[3 * j + 0];
        sy[j] = base[3 * j + 1];
        sz[j] = base[3 * j + 2];
    }
    __syncthreads();
    const int wid = threadIdx.x >> 6, lane = threadIdx.x & 63;
    const int q0 = qblk + wid * QW;
    double qx[QW], qy[QW], qz[QW], bv[QW];
    int bi[QW];
#pragma unroll
    for (int q = 0; q < QW; ++q) {
        qx[q] = (double)sx[q0 + q];
        qy[q] = (double)sy[q0 + q];
        qz[q] = (double)sz[q0 + q];
        bv[q] = -1e300;
        bi[q] = 0;
    }
#pragma unroll 4
    for (int ch = 0; ch < N / 64; ++ch) {
        const int j = ch * 64 + lane;
        const double xd = (double)sx[j], yd = (double)sy[j], zd = (double)sz[j];
#pragma unroll
        for (int q = 0; q < QW; ++q) {
            double dx = qx[q] - xd, dy = qy[q] - yd, dz = qz[q] - zd;
            double pd = -(dx * dx + dy * dy + dz * dz);
            bool upd = (pd > bv[q]) && (j != q0 + q);
            bv[q] = upd ? pd : bv[q];
            bi[q] = upd ? j : bi[q];
        }
    }
#pragma unroll
    for (int q = 0; q < QW; ++q) {
#pragma unroll
        for (int m = 1; m < 64; m <<= 1) {
            double ov = __shfl_xor(bv[q], m, 64);
            int oi = __shfl_xor(bi[q], m, 64);
            bool take = (ov > bv[q]) || (ov == bv[q] && oi < bi[q]);
            bv[q] = take ? ov : bv[q];
            bi[q] = take ? oi : bi[q];
        }
    }
    if (lane == 0) {
        int* o = nbrbest + (size_t)b * N + q0;
        o[0] = bi[0]; o[1] = bi[1]; o[2] = bi[2]; o[3] = bi[3];
    }
}

// ---------------- K2: layer0 BN stats ----------------------------------------------
__global__ __launch_bounds__(256) void k_st0(const float* __restrict__ pc,
                                             const int* __restrict__ nbr,
                                             const float* __restrict__ Wf0,
                                             double* __restrict__ st0) {
    __shared__ float wf0[63], red[168];
    if (threadIdx.x < 63) wf0[threadIdx.x] = Wf0[threadIdx.x];
    __syncthreads();
    const int tid = blockIdx.x * 256 + threadIdx.x;
    Feat f = make_feat(pc, nbr, tid);
    float sv[42];
#pragma unroll
    for (int o = 0; o < 21; ++o) {
        float w0 = wf0[3 * o], w1 = wf0[3 * o + 1], w2 = wf0[3 * o + 2];
        float pSx = w1 * f.cx, pSy = w1 * f.cy, pSz = w1 * f.cz;
        float nS = sqrtf(pSx * pSx + pSy * pSy + pSz * pSz) + EPSF;
        float px = w0 * f.e0x + w1 * f.cx + w2 * f.e2x;
        float py = w0 * f.e0y + w1 * f.cy + w2 * f.e2y;
        float pz = w0 * f.e0z + w1 * f.cz + w2 * f.e2z;
        float nN = sqrtf(px * px + py * py + pz * pz) + EPSF;
        sv[o] = nS + nN;
        sv[21 + o] = nS * nS + nN * nN;
    }
    block_stats<42>(sv, red, st0);
}

// ---------------- K3: layer1 BN stats ----------------------------------------------
__global__ __launch_bounds__(256) void k_st1(
    const float* __restrict__ pc, const int* __restrict__ nbr,
    const float* __restrict__ Wf0, const float* __restrict__ Wd0,
    const float* __restrict__ g0, const float* __restrict__ b0,
    const float* __restrict__ Wf1, const double* __restrict__ st0,
    double* __restrict__ st1) {
    __shared__ float wf0[63], wd0[63], wf1[441];
    __shared__ float g0s[21], b0s[21], mu0[21], isd0[21], red[168];
    if (threadIdx.x < 63) { wf0[threadIdx.x] = Wf0[threadIdx.x]; wd0[threadIdx.x] = Wd0[threadIdx.x]; }
    for (int i = threadIdx.x; i < 441; i += 256) wf1[i] = Wf1[i];
    if (threadIdx.x < 21) { g0s[threadIdx.x] = g0[threadIdx.x]; b0s[threadIdx.x] = b0[threadIdx.x]; }
    mk_muisd(st0, 21, (double)B * N * 2.0, mu0, isd0);
    __syncthreads();
    const int tid = blockIdx.x * 256 + threadIdx.x;
    Feat f = make_feat(pc, nbr, tid);
    float x[21][3];
    l0_apply(f, wf0, wd0, g0s, b0s, mu0, isd0, x);
    float sv[42];
#pragma unroll
    for (int o = 0; o < 21; ++o) {
        float px = 0.f, py = 0.f, pz = 0.f;
#pragma unroll
        for (int c = 0; c < 21; ++c) {
            float w = wf1[o * 21 + c];
            px += w * x[c][0]; py += w * x[c][1]; pz += w * x[c][2];
        }
        float nn = sqrtf(px * px + py * py + pz * pz) + EPSF;
        sv[o] = nn;
        sv[21 + o] = nn * nn;
    }
    block_stats<42>(sv, red, st1);
}

// ---------------- K4: bn1 stats (norms of layer1 output) ---------------------------
__global__ __launch_bounds__(256) void k_stB(
    const float* __restrict__ pc, const int* __restrict__ nbr,
    const float* __restrict__ Wf0, const float* __restrict__ Wd0,
    const float* __restrict__ g0, const float* __restrict__ b0,
    const float* __restrict__ Wf1, const float* __restrict__ Wd1,
    const float* __restrict__ g1, const float* __restrict__ b1,
    const double* __restrict__ st0, const double* __restrict__ st1,
    double* __restrict__ stB) {
    __shared__ float wf0[63], wd0[63], wf1[441], wd1[441];
    __shared__ float g0s[21], b0s[21], g1s[21], b1s[21];
    __shared__ float mu0[21], isd0[21], mu1[21], isd1[21], red[168];
    if (threadIdx.x < 63) { wf0[threadIdx.x] = Wf0[threadIdx.x]; wd0[threadIdx.x] = Wd0[threadIdx.x]; }
    for (int i = threadIdx.x; i < 441; i += 256) { wf1[i] = Wf1[i]; wd1[i] = Wd1[i]; }
    if (threadIdx.x < 21) {
        g0s[threadIdx.x] = g0[threadIdx.x]; b0s[threadIdx.x] = b0[threadIdx.x];
        g1s[threadIdx.x] = g1[threadIdx.x]; b1s[threadIdx.x] = b1[threadIdx.x];
    }
    mk_muisd(st0, 21, (double)B * N * 2.0, mu0, isd0);
    mk_muisd(st1, 21, (double)B * N, mu1, isd1);
    __syncthreads();
    const int tid = blockIdx.x * 256 + threadIdx.x;
    Feat f = make_feat(pc, nbr, tid);
    float x[21][3];
    l0_apply(f, wf0, wd0, g0s, b0s, mu0, isd0, x);
    l1_apply(x, wf1, wd1, g1s, b1s, mu1, isd1);
    float sv[42];
#pragma unroll
    for (int c = 0; c < 21; ++c) {
        float nn = sqrtf(x[c][0] * x[c][0] + x[c][1] * x[c][1] +
                         x[c][2] * x[c][2]) + EPSF;
        sv[c] = nn;
        sv[21 + c] = nn * nn;
    }
    block_stats<42>(sv, red, stB);
}

// ---------------- K5: layer2 BN stats ----------------------------------------------
__global__ __launch_bounds__(256) void k_st2(
    const float* __restrict__ pc, const int* __restrict__ nbr,
    const float* __restrict__ Wf0, const float* __restrict__ Wd0,
    const float* __restrict__ g0, const float* __restrict__ b0,
    const float* __restrict__ Wf1, const float* __restrict__ Wd1,
    const float* __restrict__ g1, const float* __restrict__ b1,
    const float* __restrict__ gbn1, const float* __restrict__ bbn1,
    const float* __restrict__ Wf2, const double* __restrict__ st0,
    const double* __restrict__ st1, const double* __restrict__ stB,
    double* __restrict__ st2) {
    __shared__ float wf0[63], wd0[63], wf1[441], wd1[441], wf2[63];
    __shared__ float g0s[21], b0s[21], g1s[21], b1s[21], gBs[21], bBs[21];
    __shared__ float mu0[21], isd0[21], mu1[21], isd1[21], muB[21], isdB[21], red[168];
    if (threadIdx.x < 63) {
        wf0[threadIdx.x] = Wf0[threadIdx.x]; wd0[threadIdx.x] = Wd0[threadIdx.x];
        wf2[threadIdx.x] = Wf2[threadIdx.x];
    }
    for (int i = threadIdx.x; i < 441; i += 256) { wf1[i] = Wf1[i]; wd1[i] = Wd1[i]; }
    if (threadIdx.x < 21) {
        g0s[threadIdx.x] = g0[threadIdx.x]; b0s[threadIdx.x] = b0[threadIdx.x];
        g1s[threadIdx.x] = g1[threadIdx.x]; b1s[threadIdx.x] = b1[threadIdx.x];
        gBs[threadIdx.x] = gbn1[threadIdx.x]; bBs[threadIdx.x] = bbn1[threadIdx.x];
    }
    mk_muisd(st0, 21, (double)B * N * 2.0, mu0, isd0);
    mk_muisd(st1, 21, (double)B * N, mu1, isd1);
    mk_muisd(stB, 21, (double)B * N, muB, isdB);
    __syncthreads();
    const int tid = blockIdx.x * 256 + threadIdx.x;
    Feat f = make_feat(pc, nbr, tid);
    float x[21][3];
    l0_apply(f, wf0, wd0, g0s, b0s, mu0, isd0, x);
    l1_apply(x, wf1, wd1, g1s, b1s, mu1, isd1);
    bn1_apply(x, gBs, bBs, muB, isdB);
    float sv[6];
#pragma unroll
    for (int o = 0; o < 3; ++o) {
        float px = 0.f, py = 0.f, pz = 0.f;
#pragma unroll
        for (int c = 0; c < 21; ++c) {
            float w = wf2[o * 21 + c];
            px += w * x[c][0]; py += w * x[c][1]; pz += w * x[c][2];
        }
        float nn = sqrtf(px * px + py * py + pz * pz) + EPSF;
        sv[o] = nn;
        sv[3 + o] = nn * nn;
    }
    block_stats<6>(sv, red, st2);
}

// ---------------- K6: layer2 apply + per-batch accumulation ------------------------
__global__ __launch_bounds__(256) void k_acc(
    const float* __restrict__ pc, const int* __restrict__ nbr,
    const float* __restrict__ Wf0, const float* __restrict__ Wd0,
    const float* __restrict__ g0, const float* __restrict__ b0,
    const float* __restrict__ Wf1, const float* __restrict__ Wd1,
    const float* __restrict__ g1, const float* __restrict__ b1,
    const float* __restrict__ gbn1, const float* __restrict__ bbn1,
    const float* __restrict__ Wf2, const float* __restrict__ Wd2,
    const float* __restrict__ g2, const float* __restrict__ b2,
    const double* __restrict__ st0, const double* __restrict__ st1,
    const double* __restrict__ stB, const double* __restrict__ st2,
    double* __restrict__ acc) {
    __shared__ float wf0[63], wd0[63], wf1[441], wd1[441], wf2[63], wd2[63];
    __shared__ float g0s[21], b0s[21], g1s[21], b1s[21], gBs[21], bBs[21], g2s[3], b2s[3];
    __shared__ float mu0[21], isd0[21], mu1[21], isd1[21], muB[21], isdB[21], mu2[3], isd2[3];
    __shared__ float red[168];
    if (threadIdx.x < 63) {
        wf0[threadIdx.x] = Wf0[threadIdx.x]; wd0[threadIdx.x] = Wd0[threadIdx.x];
        wf2[threadIdx.x] = Wf2[threadIdx.x]; wd2[threadIdx.x] = Wd2[threadIdx.x];
    }
    for (int i = threadIdx.x; i < 441; i += 256) { wf1[i] = Wf1[i]; wd1[i] = Wd1[i]; }
    if (threadIdx.x < 21) {
        g0s[threadIdx.x] = g0[threadIdx.x]; b0s[threadIdx.x] = b0[threadIdx.x];
        g1s[threadIdx.x] = g1[threadIdx.x]; b1s[threadIdx.x] = b1[threadIdx.x];
        gBs[threadIdx.x] = gbn1[threadIdx.x]; bBs[threadIdx.x] = bbn1[threadIdx.x];
    }
    if (threadIdx.x < 3) { g2s[threadIdx.x] = g2[threadIdx.x]; b2s[threadIdx.x] = b2[threadIdx.x]; }
    mk_muisd(st0, 21, (double)B * N * 2.0, mu0, isd0);
    mk_muisd(st1, 21, (double)B * N, mu1, isd1);
    mk_muisd(stB, 21, (double)B * N, muB, isdB);
    mk_muisd(st2, 3, (double)B * N, mu2, isd2);
    __syncthreads();
    const int tid = blockIdx.x * 256 + threadIdx.x;
    Feat f = make_feat(pc, nbr, tid);
    float x[21][3];
    l0_apply(f, wf0, wd0, g0s, b0s, mu0, isd0, x);
    l1_apply(x, wf1, wd1, g1s, b1s, mu1, isd1);
    bn1_apply(x, gBs, bBs, muB, isdB);
    float sv[9];
#pragma unroll
    for (int o = 0; o < 3; ++o) {
        float px = 0.f, py = 0.f, pz = 0.f, dx = 0.f, dy = 0.f, dz = 0.f;
#pragma unroll
        for (int c = 0; c < 21; ++c) {
            float w = wf2[o * 21 + c], u = wd2[o * 21 + c];
            px += w * x[c][0]; py += w * x[c][1]; pz += w * x[c][2];
            dx += u * x[c][0]; dy += u * x[c][1]; dz += u * x[c][2];
        }
        float nn = sqrtf(px * px + py * py + pz * pz) + EPSF;
        float s = ((nn - mu2[o]) * isd2[o] * g2s[o] + b2s[o]) / nn;
        leaky3(px, py, pz, dx, dy, dz, s, sv[3 * o], sv[3 * o + 1], sv[3 * o + 2]);
    }
    const int bb_ = blockIdx.x >> 4;
    block_stats<9>(sv, red, acc + bb_ * 9);
}

// ---------------- K7: finalize ------------------------------------------------------
__global__ void k_fin(const double* __restrict__ acc, float* __restrict__ out) {
    if (threadIdx.x < B * 9)
        out[threadIdx.x] = (float)(acc[threadIdx.x] * (1.0 / (double)N));
}

extern "C" void kernel_launch(void* const* d_in, const int* in_sizes, int n_in,
                              void* d_out, int out_size, void* d_ws, size_t ws_size,
                              hipStream_t stream) {
    const float* pc = (const float*)d_in[0];
    const float* Wf0 = (const float*)d_in[1];
    const float* Wd0 = (const float*)d_in[2];
    const float* g0 = (const float*)d_in[3];
    const float* b0 = (const float*)d_in[4];
    const float* Wf1 = (const float*)d_in[5];
    const float* Wd1 = (const float*)d_in[6];
    const float* g1 = (const float*)d_in[7];
    const float* b1 = (const float*)d_in[8];
    const float* gbn1 = (const float*)d_in[9];
    const float* bbn1 = (const float*)d_in[10];
    const float* Wf2 = (const float*)d_in[11];
    const float* Wd2 = (const float*)d_in[12];
    const float* g2 = (const float*)d_in[13];
    const float* b2 = (const float*)d_in[14];
    float* out = (float*)d_out;

    char* ws = (char*)d_ws;
    double* st0 = (double*)ws;          // 42
    double* st1 = st0 + 42;             // 42
    double* stB = st1 + 42;             // 42
    double* st2 = stB + 42;             // 6
    double* acc = st2 + 6;              // 144  (total 276 doubles < 4096 B)
    int* nbrbest = (int*)(ws + 4096);   // B*N ints

    hipMemsetAsync(d_ws, 0, 4096, stream);

    k_knn<<<B * (N / 16), 256, 0, stream>>>(pc, nbrbest);
    k_st0<<<B * N / 256, 256, 0, stream>>>(pc, nbrbest, Wf0, st0);
    k_st1<<<B * N / 256, 256, 0, stream>>>(pc, nbrbest, Wf0, Wd0, g0, b0, Wf1, st0, st1);
    k_stB<<<B * N / 256, 256, 0, stream>>>(pc, nbrbest, Wf0, Wd0, g0, b0, Wf1, Wd1,
                                           g1, b1, st0, st1, stB);
    k_st2<<<B * N / 256, 256, 0, stream>>>(pc, nbrbest, Wf0, Wd0, g0, b0, Wf1, Wd1,
                                           g1, b1, gbn1, bbn1, Wf2, st0, st1, stB, st2);
    k_acc<<<B * N / 256, 256, 0, stream>>>(pc, nbrbest, Wf0, Wd0, g0, b0, Wf1, Wd1,
                                           g1, b1, gbn1, bbn1, Wf2, Wd2, g2, b2,
                                           st0, st1, stB, st2, acc);
    k_fin<<<1, 256, 0, stream>>>(acc, out);
}